// Round 4
// baseline (93.643 us; speedup 1.0000x reference)
//
#include <hip/hip_runtime.h>
#include <math.h>

#define LOG2E  1.44269504088896340736f
#define LN2    0.69314718055994530942f
#define LOG2PI 1.8378770664093453f

#define N 2048
#define D 64

// single-instruction transcendentals (v_exp_f32 / v_log_f32)
__device__ __forceinline__ float fexp2(float x) { return __builtin_amdgcn_exp2f(x); }
__device__ __forceinline__ float flog2(float x) { return __builtin_amdgcn_logf(x); }

// ---------------------------------------------------------------------------
// K1: derived arrays. a*log2e = (z-mean)^2*p + c22 = z2*p + z*q + r2 with
//   p = -0.5*exp(-lv)*log2e, q = -2*mean*p, c22 = -0.5*(lv+LOG2PI)*log2e,
//   r2 = mean^2*p + c22.
// Outputs:
//   packed[j*64+d] = {mean, p, c22, 0}     (K3, coalesced in d)
//   pqT[d*N+j]     = {p, q}                (K2 scalar operands, contig in j)
//   zzT[d*N+i]     = {z, z^2}              (K2 per-lane coalesced loads)
//   r[j] = sum_d r2
// ---------------------------------------------------------------------------
__global__ __launch_bounds__(1024) void k1_precompute(
    const float* __restrict__ z, const float* __restrict__ z_mean,
    const float* __restrict__ z_lv,
    float4* __restrict__ packed, float2* __restrict__ pqT,
    float2* __restrict__ zzT, float* __restrict__ r)
{
    __shared__ float aL[64][65], bL[64][65], cL[64][65];
    int tid  = threadIdx.x;
    int lane = tid & 63;     // d in compute phases, j/i in store phases
    int row  = tid >> 6;     // 0..15
    int jb   = blockIdx.x * 64;

    // Phase A: compute; coalesced packed store; stash p,q,r2 in LDS
    #pragma unroll
    for (int ppp = 0; ppp < 4; ++ppp) {
        int jl  = ppp * 16 + row;
        int idx = (jb + jl) * D + lane;
        float mean = z_mean[idx], lv = z_lv[idx];
        float p   = -0.5f * fexp2(-lv * LOG2E) * LOG2E;
        float q   = -2.0f * mean * p;
        float c22 = -0.5f * (lv + LOG2PI) * LOG2E;
        float r2  = fmaf(mean * mean, p, c22);
        packed[idx] = make_float4(mean, p, c22, 0.0f);
        aL[jl][lane] = p; bL[jl][lane] = q; cL[jl][lane] = r2;
    }
    __syncthreads();
    // Phase B: transposed pq store, coalesced in j
    #pragma unroll
    for (int ppp = 0; ppp < 4; ++ppp) {
        int dd = ppp * 16 + row;
        pqT[(size_t)dd * N + jb + lane] = make_float2(aL[lane][dd], bL[lane][dd]);
    }
    // Phase C: r[j] = sum_d r2
    if (tid < 64) {
        float s = 0.0f;
        #pragma unroll
        for (int dd = 0; dd < 64; ++dd) s += cL[tid][dd];
        r[jb + tid] = s;
    }
    __syncthreads();
    // Phase D: stash z, z^2 (reuse aL,bL)
    #pragma unroll
    for (int ppp = 0; ppp < 4; ++ppp) {
        int jl  = ppp * 16 + row;
        int idx = (jb + jl) * D + lane;
        float zv = z[idx];
        aL[jl][lane] = zv; bL[jl][lane] = zv * zv;
    }
    __syncthreads();
    #pragma unroll
    for (int ppp = 0; ppp < 4; ++ppp) {
        int dd = ppp * 16 + row;
        zzT[(size_t)dd * N + jb + lane] = make_float2(aL[lane][dd], bL[lane][dd]);
    }
}

// ---------------------------------------------------------------------------
// K3: sums[jq][i][d] = sum_{j in quarter jq} 2^{(z-mean)^2*p + c22}
// (fixed max M=0: args <= ~1.2 in log2; underflow-to-0 harmless — merged
//  total per (i,d) is lower-bounded via the j~i terms.)
// Block: 1024 thr = 16 waves; i-tile 16; wave owns a 32-j slice; lane = d.
// Grid: 128 i-tiles x 4 j-quarters = 512 blocks = 2 blocks/CU (100% occ).
// ~48 VGPR target: only zr[16]+s[16] live (no z2), no forced min-occupancy.
// ---------------------------------------------------------------------------
__global__ __launch_bounds__(1024) void k3_perd(
    const float* __restrict__ z, const float4* __restrict__ packed,
    float* __restrict__ sums)
{
    __shared__ float sm[16][16][D];   // 64 KB
    int lane = threadIdx.x & 63;
    int w    = threadIdx.x >> 6;      // 0..15
    int tile = blockIdx.x >> 2;
    int jq   = blockIdx.x & 3;
    int i0   = tile * 16;

    float zr[16], s[16];
    #pragma unroll
    for (int i = 0; i < 16; ++i) {
        zr[i] = z[(i0 + i) * D + lane];
        s[i]  = 0.0f;
    }

    const float4* pk = packed + ((size_t)(jq * 512 + w * 32)) * D + lane;
    #pragma unroll 2
    for (int jj = 0; jj < 32; ++jj) {
        float4 c = pk[(size_t)jj * D];   // {mean, p, c22, -}
        #pragma unroll
        for (int i = 0; i < 16; ++i) {
            float diff = zr[i] - c.x;
            float dp   = diff * c.y;
            s[i] += fexp2(fmaf(diff, dp, c.z));
        }
    }

    #pragma unroll
    for (int i = 0; i < 16; ++i) sm[i][w][lane] = s[i];
    __syncthreads();

    // wave w finishes row i0+w
    float tot = 0.0f;
    #pragma unroll
    for (int w2 = 0; w2 < 16; ++w2) tot += sm[w][w2][lane];
    sums[((size_t)jq * N + i0 + w) * D + lane] = tot;
}

// ---------------------------------------------------------------------------
// K2: b2[i,j] = sum_d z2*p + z*q; partial LSE over a 16-j tile per thread.
// i = lane (coalesced float2 zzT loads); j-tile block-uniform so pqT/r are
// true scalar loads (address has no threadIdx dependence -> s_load).
// Grid: 4 i-blocks x 128 j-tiles = 512 blocks x 512 thr (4 waves/SIMD).
// ---------------------------------------------------------------------------
__global__ __launch_bounds__(512) void k2_logqz(
    const float2* __restrict__ zzT, const float2* __restrict__ pqT,
    const float* __restrict__ r, float2* __restrict__ k2ms)
{
    int tid = threadIdx.x;
    int ib  = blockIdx.x & 3;
    int jq  = blockIdx.x >> 2;       // 0..127
    int i   = ib * 512 + tid;
    int j0  = jq * 16;

    float acc[16];
    #pragma unroll
    for (int jj = 0; jj < 16; ++jj) acc[jj] = 0.0f;

    #pragma unroll 2
    for (int d = 0; d < D; ++d) {
        float2 zz = zzT[(size_t)d * N + i];     // {z, z^2}
        #pragma unroll
        for (int jj = 0; jj < 16; ++jj) {
            float2 pq = pqT[(size_t)d * N + j0 + jj];   // uniform -> s_load
            acc[jj] = fmaf(zz.y, pq.x, fmaf(zz.x, pq.y, acc[jj]));
        }
    }

    // online LSE (log2 domain) over the 16 j's
    float mm = -1e30f, ss = 0.0f;
    #pragma unroll
    for (int jj = 0; jj < 16; ++jj) {
        float b  = acc[jj] + r[j0 + jj];        // r: uniform -> s_load
        float mn = fmaxf(mm, b);
        ss = ss * fexp2(mm - mn) + fexp2(b - mn);
        mm = mn;
    }
    k2ms[(size_t)jq * N + i] = make_float2(mm, ss);
}

// ---------------------------------------------------------------------------
// K5: per i: lqp[i] = ln2 * sum_d log2(sum_q sums[q][i][d]);
//            lq[i]  = ln2 * LSE-merge of 128 (m,s) partials;
//            diff[i] = lqp - lq.
// Block: 256 thr, 32 i's. Grid: 64.
// ---------------------------------------------------------------------------
__global__ __launch_bounds__(256) void k5_merge(
    const float* __restrict__ sums, const float2* __restrict__ k2ms,
    float* __restrict__ diff)
{
    __shared__ float lqpL[32];
    __shared__ float pmL[8][32], psL[8][32];
    int tid = threadIdx.x, lane = tid & 63, w = tid >> 6;  // 4 waves
    int i0 = blockIdx.x * 32;

    // Phase A: wave w handles i = i0 + w*8 + ii, lane = d
    #pragma unroll
    for (int ii = 0; ii < 8; ++ii) {
        int i = i0 + w * 8 + ii;
        float tot = 0.0f;
        #pragma unroll
        for (int q = 0; q < 4; ++q)
            tot += sums[((size_t)q * N + i) * D + lane];
        float t = flog2(tot);
        #pragma unroll
        for (int off = 32; off; off >>= 1) t += __shfl_xor(t, off, 64);
        if (lane == 0) lqpL[w * 8 + ii] = LN2 * t;
    }
    __syncthreads();

    // Phase B: thread (g, ii) merges 16 of the 128 partials for i0+ii
    int ii = tid & 31, g = tid >> 5;   // g 0..7
    int i = i0 + ii;
    float mm = -1e30f, ss = 0.0f;
    #pragma unroll
    for (int t2 = 0; t2 < 16; ++t2) {
        float2 p = k2ms[(size_t)(g * 16 + t2) * N + i];
        float mn = fmaxf(mm, p.x);
        ss = ss * fexp2(mm - mn) + p.y * fexp2(p.x - mn);
        mm = mn;
    }
    pmL[g][ii] = mm; psL[g][ii] = ss;
    __syncthreads();

    if (tid < 32) {
        float m2 = pmL[0][tid], s2 = psL[0][tid];
        #pragma unroll
        for (int g2 = 1; g2 < 8; ++g2) {
            float m3 = pmL[g2][tid], s3 = psL[g2][tid];
            float mn = fmaxf(m2, m3);
            s2 = s2 * fexp2(m2 - mn) + s3 * fexp2(m3 - mn);
            m2 = mn;
        }
        diff[i0 + tid] = lqpL[tid] - LN2 * (m2 + flog2(s2));
    }
}

// ---------------------------------------------------------------------------
// K6: out = mean_i diff[i]
// ---------------------------------------------------------------------------
__global__ __launch_bounds__(256) void k6_final(
    const float* __restrict__ diff, float* __restrict__ out)
{
    __shared__ float red[256];
    int tid = threadIdx.x;
    float t = 0.0f;
    for (int k = tid; k < N; k += 256) t += diff[k];
    red[tid] = t;
    __syncthreads();
    #pragma unroll
    for (int off = 128; off; off >>= 1) {
        if (tid < off) red[tid] += red[tid + off];
        __syncthreads();
    }
    if (tid == 0) out[0] = red[0] * (1.0f / (float)N);
}

extern "C" void kernel_launch(void* const* d_in, const int* in_sizes, int n_in,
                              void* d_out, int out_size, void* d_ws, size_t ws_size,
                              hipStream_t stream)
{
    const float* z      = (const float*)d_in[0];
    const float* z_mean = (const float*)d_in[1];
    const float* z_lv   = (const float*)d_in[2];
    float* out = (float*)d_out;

    float* ws = (float*)d_ws;
    float4* packed = (float4*)ws;                    // N*D float4 (2 MB)
    float*  base   = ws + (size_t)N * D * 4;
    float2* pqT    = (float2*)base;                  // N*D float2 (1 MB)
    float2* zzT    = (float2*)(base + (size_t)N * D * 2);  // N*D float2 (1 MB)
    float*  r      = base + (size_t)N * D * 4;       // N
    float*  sums   = r + N;                          // 4*N*D (2 MB)
    float*  k2ms_f = sums + (size_t)4 * N * D;       // 128*N float2 (2 MB)
    float2* k2ms   = (float2*)k2ms_f;
    float*  diff   = k2ms_f + (size_t)256 * N;       // N

    k1_precompute<<<N / 64, 1024, 0, stream>>>(z, z_mean, z_lv, packed, pqT, zzT, r);
    k3_perd<<<512, 1024, 0, stream>>>(z, packed, sums);
    k2_logqz<<<512, 512, 0, stream>>>(zzT, pqT, r, k2ms);
    k5_merge<<<N / 32, 256, 0, stream>>>(sums, k2ms, diff);
    k6_final<<<1, 256, 0, stream>>>(diff, out);
}